// Round 3
// baseline (136.120 us; speedup 1.0000x reference)
//
#include <hip/hip_runtime.h>
#include <math.h>
#include <string.h>

constexpr int VOCAB  = 32000;
constexpr int D      = 128;
constexpr int T      = 32;
constexpr int NCELLS = 8 * 100 * 64;   // 51200
constexpr int NCHUNK = 4;              // D split into 4 chunks of 32 dims
constexpr int CDIM   = D / NCHUNK;     // 32 dims per chunk (64 B bf16 rows)

// ---- bf16 helpers (manual RTN-even)
__device__ inline ushort f2bf(float f) {
    uint32_t u;
    memcpy(&u, &f, 4);
    u += 0x7FFFu + ((u >> 16) & 1u);
    return (ushort)(u >> 16);
}
__device__ inline float bf2f(ushort h) {
    uint32_t u = ((uint32_t)h) << 16;
    float f;
    memcpy(&f, &u, 4);
    return f;
}

// Kernel 1: convert W_embed f32 -> bf16, CHUNKED layout:
// Wb[chunk][vocab][32 dims]. One thread per 4 source elements.
__global__ __launch_bounds__(256) void convert_W_kernel(
    const float* __restrict__ W, ushort* __restrict__ Wb)
{
    const int i = blockIdx.x * blockDim.x + threadIdx.x;  // [0, VOCAB*D/4)
    const int v = i >> 5;        // vocab row
    const int k = i & 31;        // which ushort4 group (dims 4k..4k+3)
    const int chunk = k >> 3;
    const int sub   = k & 7;

    float4 src = reinterpret_cast<const float4*>(W)[i];
    ushort4 o;
    o.x = f2bf(src.x); o.y = f2bf(src.y); o.z = f2bf(src.z); o.w = f2bf(src.w);
    reinterpret_cast<ushort4*>(Wb)[(size_t)chunk * (VOCAB * 8) + (size_t)v * 8 + sub] = o;
}

// Kernel 2: one wave per (cell, chunk). chunk is steered by blockIdx%8 so each
// XCD's L2 only caches one 2.05 MB table slice.
// Within a wave: quarter q = lane>>4 handles tokens {4i+q}, lanes h = lane&15
// cover the chunk's 32 dims as ushort2 (4 B/lane, 64 B per row access).
__global__ __launch_bounds__(256) void gather_kernel(
    const int*    __restrict__ x,       // [NCELLS, T]
    const ushort* __restrict__ Wb,      // [NCHUNK][VOCAB][CDIM] bf16 bits
    const float*  __restrict__ w_pred,  // [1, D]
    const float*  __restrict__ b_pred,  // [1]
    float*        __restrict__ out)     // [NCELLS] (pre-zeroed)
{
    const int wave = threadIdx.x >> 6;
    const int lane = threadIdx.x & 63;

    const int slot  = blockIdx.x & 7;          // ~XCD id (dispatch heuristic)
    const int chunk = slot >> 1;               // 2 XCDs per chunk
    const int g     = blockIdx.x >> 3;         // 0..6399
    const int cell  = ((g << 1) + (slot & 1)) * 4 + wave;   // 0..51199

    const int h = lane & 15;   // dim pair index within chunk: dims 2h, 2h+1
    const int q = lane >> 4;   // token quarter

    // token ids (non-temporal: streamed once, don't thrash the table slice)
    int myidx = __builtin_nontemporal_load(x + (size_t)cell * T + (lane & 31));

    const ushort2* __restrict__ base =
        reinterpret_cast<const ushort2*>(Wb + (size_t)chunk * VOCAB * CDIM);

    float a0 = 0.f, a1 = 0.f;
    #pragma unroll
    for (int i = 0; i < T / 4; ++i) {
        int row = __shfl(myidx, i * 4 + q, 64);
        ushort2 v = base[(size_t)row * (CDIM / 2) + h];
        a0 += bf2f(v.x);
        a1 += bf2f(v.y);
    }
    // combine the 4 token-quarters (same dims, disjoint tokens)
    a0 += __shfl_xor(a0, 32, 64);
    a1 += __shfl_xor(a1, 32, 64);
    a0 += __shfl_xor(a0, 16, 64);
    a1 += __shfl_xor(a1, 16, 64);

    const float inv_t = 1.0f / (float)T;
    float p0 = a0 * inv_t;
    float p1 = a1 * inv_t;

    const float is2 = 0.70710678118654752440f;
    float g0 = 0.5f * p0 * (1.0f + erff(p0 * is2));
    float g1 = 0.5f * p1 * (1.0f + erff(p1 * is2));

    float2 wv = reinterpret_cast<const float2*>(w_pred)[chunk * (CDIM / 2) + h];
    float s = g0 * wv.x + g1 * wv.y;

    // reduce over the 16 dim-pairs (values duplicated across quarters)
    #pragma unroll
    for (int off = 8; off >= 1; off >>= 1)
        s += __shfl_xor(s, off, 64);

    if (lane == 0) {
        if (chunk == 0) s += b_pred[0];
        atomicAdd(&out[cell], s);
    }
}

extern "C" void kernel_launch(void* const* d_in, const int* in_sizes, int n_in,
                              void* d_out, int out_size, void* d_ws, size_t ws_size,
                              hipStream_t stream) {
    const int*   x      = (const int*)  d_in[0];
    const float* W      = (const float*)d_in[1];
    const float* w_pred = (const float*)d_in[2];
    const float* b_pred = (const float*)d_in[3];
    float*       out    = (float*)d_out;
    ushort*      Wb     = (ushort*)d_ws;   // VOCAB*D*2 = 8.192 MB

    const int conv_groups = VOCAB * D / 4;                 // 1,024,000
    convert_W_kernel<<<conv_groups / 256, 256, 0, stream>>>(W, Wb);

    hipMemsetAsync(out, 0, (size_t)NCELLS * sizeof(float), stream);

    // 4 chunks x 12800 cell-groups (4 cells per block) = 51200 blocks
    gather_kernel<<<NCHUNK * (NCELLS / 4), 256, 0, stream>>>(x, Wb, w_pred, b_pred, out);
}

// Round 4
// 114.946 us; speedup vs baseline: 1.1842x; 1.1842x over previous
//
#include <hip/hip_runtime.h>
#include <math.h>
#include <string.h>

constexpr int VOCAB  = 32000;
constexpr int D      = 128;
constexpr int T      = 32;
constexpr int NCELLS = 8 * 100 * 64;   // 51200
constexpr int NCHUNK = 2;              // D split into 2 chunks of 64 dims
constexpr int CDIM   = D / NCHUNK;     // 64 dims per chunk (128 B bf16 rows)

// ---- bf16 helpers
__device__ inline ushort f2bf(float f) {
    uint32_t u;
    memcpy(&u, &f, 4);
    u += 0x7FFFu + ((u >> 16) & 1u);   // RTN-even
    return (ushort)(u >> 16);
}
__device__ inline float hi16_to_f(uint32_t bits) {
    float f;
    memcpy(&f, &bits, 4);
    return f;
}

// Fast exact-erf GELU: Abramowitz-Stegun 7.1.26 (|erf err| <= 1.5e-7), hw rcp/exp.
__device__ inline float gelu_fast(float xv) {
    const float is2 = 0.70710678118654752440f;
    float y  = xv * is2;
    float ay = fabsf(y);
    float t  = __builtin_amdgcn_rcpf(__builtin_fmaf(0.3275911f, ay, 1.0f));
    float p  = 0.254829592f + t * (-0.284496736f + t * (1.421413741f
             + t * (-1.453152027f + t * 1.061405429f)));
    float e  = __expf(-ay * ay);
    float er = 1.0f - p * t * e;           // erf(|y|)
    er = copysignf(er, y);
    return 0.5f * xv * (1.0f + er);
}

// Kernel 1: convert W_embed f32 -> bf16, chunked layout Wb[chunk][vocab][CDIM].
__global__ __launch_bounds__(256) void convert_W_kernel(
    const float* __restrict__ W, ushort* __restrict__ Wb)
{
    const int i = blockIdx.x * blockDim.x + threadIdx.x;  // ushort4 group id
    const int v = i >> 5;        // vocab row   (32 groups of 4 dims per row)
    const int k = i & 31;
    const int chunk = k >> 4;    // 16 groups per chunk
    const int sub   = k & 15;

    float4 src = reinterpret_cast<const float4*>(W)[i];
    ushort4 o;
    o.x = f2bf(src.x); o.y = f2bf(src.y); o.z = f2bf(src.z); o.w = f2bf(src.w);
    reinterpret_cast<ushort4*>(Wb)[(size_t)chunk * (VOCAB * 16) + (size_t)v * 16 + sub] = o;
}

// Kernel 2: one wave per (cell, chunk). blockIdx%8 steers: XCDs 0-3 -> chunk 0,
// XCDs 4-7 -> chunk 1, so each XCD L2 caches one 4.1 MB slice.
// Lane: h = lane&15 -> dims 4h..4h+3 of the chunk (uint2 = 8B load),
//       q = lane>>4 -> token quarter {q, q+4, ..., q+28}.
__global__ __launch_bounds__(256) void gather_kernel(
    const int*    __restrict__ x,       // [NCELLS, T]
    const ushort* __restrict__ Wb,      // [NCHUNK][VOCAB][CDIM] bf16 bits
    const float*  __restrict__ w_pred,  // [1, D]
    const float*  __restrict__ b_pred,  // [1]
    float*        __restrict__ out)     // [NCELLS] (pre-zeroed)
{
    const int wave = threadIdx.x >> 6;
    const int lane = threadIdx.x & 63;

    const int slot  = blockIdx.x & 7;          // ~XCD id
    const int chunk = slot >> 2;               // 4 XCDs per chunk
    const int sub   = slot & 3;
    const int g     = blockIdx.x >> 3;         // 0..3199
    const int cell  = ((g << 2) + sub) * 4 + wave;   // 0..51199

    const int h = lane & 15;
    const int q = lane >> 4;

    int myidx = __builtin_nontemporal_load(x + (size_t)cell * T + (lane & 31));

    const uint2* __restrict__ base =
        reinterpret_cast<const uint2*>(Wb) + (size_t)chunk * (VOCAB * 16) + h;

    float a0 = 0.f, a1 = 0.f, a2 = 0.f, a3 = 0.f;
    #pragma unroll
    for (int i = 0; i < T / 4; ++i) {
        int row = __shfl(myidx, i * 4 + q, 64);
        uint2 u = base[(size_t)row * 16];
        a0 += hi16_to_f(u.x << 16);
        a1 += hi16_to_f(u.x & 0xffff0000u);
        a2 += hi16_to_f(u.y << 16);
        a3 += hi16_to_f(u.y & 0xffff0000u);
    }
    // combine the 4 token-quarters
    a0 += __shfl_xor(a0, 32, 64);
    a1 += __shfl_xor(a1, 32, 64);
    a2 += __shfl_xor(a2, 32, 64);
    a3 += __shfl_xor(a3, 32, 64);
    a0 += __shfl_xor(a0, 16, 64);
    a1 += __shfl_xor(a1, 16, 64);
    a2 += __shfl_xor(a2, 16, 64);
    a3 += __shfl_xor(a3, 16, 64);

    const float inv_t = 1.0f / (float)T;
    float g0 = gelu_fast(a0 * inv_t);
    float g1 = gelu_fast(a1 * inv_t);
    float g2 = gelu_fast(a2 * inv_t);
    float g3 = gelu_fast(a3 * inv_t);

    float4 wv = reinterpret_cast<const float4*>(w_pred)[chunk * 16 + h];
    float s = g0 * wv.x + g1 * wv.y + g2 * wv.z + g3 * wv.w;

    // reduce over the 16 dim-groups
    #pragma unroll
    for (int off = 8; off >= 1; off >>= 1)
        s += __shfl_xor(s, off, 64);

    if (lane == 0) {
        if (chunk == 0) s += b_pred[0];
        atomicAdd(&out[cell], s);
    }
}

extern "C" void kernel_launch(void* const* d_in, const int* in_sizes, int n_in,
                              void* d_out, int out_size, void* d_ws, size_t ws_size,
                              hipStream_t stream) {
    const int*   x      = (const int*)  d_in[0];
    const float* W      = (const float*)d_in[1];
    const float* w_pred = (const float*)d_in[2];
    const float* b_pred = (const float*)d_in[3];
    float*       out    = (float*)d_out;
    ushort*      Wb     = (ushort*)d_ws;   // VOCAB*D*2 = 8.192 MB

    const int conv_groups = VOCAB * D / 4;                 // 1,024,000
    convert_W_kernel<<<conv_groups / 256, 256, 0, stream>>>(W, Wb);

    hipMemsetAsync(out, 0, (size_t)NCELLS * sizeof(float), stream);

    // 2 chunks x 12800 cell-blocks (4 cells per block) = 25600 blocks
    gather_kernel<<<NCHUNK * (NCELLS / 4), 256, 0, stream>>>(x, Wb, w_pred, b_pred, out);
}

// Round 5
// 106.191 us; speedup vs baseline: 1.2818x; 1.0824x over previous
//
#include <hip/hip_runtime.h>
#include <hip/hip_bf16.h>
#include <math.h>
#include <string.h>

constexpr int VOCAB  = 32000;
constexpr int D      = 128;
constexpr int T      = 32;
constexpr int NCELLS = 8 * 100 * 64;   // 51200
constexpr int NCHUNK = 2;              // D split into 2 chunks of 64 dims
constexpr int CDIM   = D / NCHUNK;     // 64 dims (128 B bf16 per row slice)
constexpr int CHUNK_ELEMS2 = VOCAB * (CDIM / 2);  // bf162 elems per chunk slice

// ---- helpers
__device__ inline ushort f2bf(float f) {
    uint32_t u;
    memcpy(&u, &f, 4);
    u += 0x7FFFu + ((u >> 16) & 1u);   // RTN-even
    return (ushort)(u >> 16);
}

// Fast exact-erf GELU: Abramowitz-Stegun 7.1.26 (|erf err| <= 1.5e-7).
__device__ inline float gelu_fast(float xv) {
    const float is2 = 0.70710678118654752440f;
    float y  = xv * is2;
    float av = fabsf(y);
    float t  = __builtin_amdgcn_rcpf(__builtin_fmaf(0.3275911f, av, 1.0f));
    float p  = 0.254829592f + t * (-0.284496736f + t * (1.421413741f
             + t * (-1.453152027f + t * 1.061405429f)));
    float e  = __expf(-av * av);
    float er = 1.0f - p * t * e;
    er = copysignf(er, y);
    return 0.5f * xv * (1.0f + er);
}

// Kernel 1: convert W_embed f32 -> bf16 chunked [chunk][vocab][CDIM]; also
// zero-init out (grid covers 1.024M threads >= NCELLS).
__global__ __launch_bounds__(256) void convert_W_kernel(
    const float* __restrict__ W, ushort* __restrict__ Wb, float* __restrict__ out)
{
    const int i = blockIdx.x * blockDim.x + threadIdx.x;  // ushort4 group id
    const int v = i >> 5;        // vocab row (32 groups of 4 dims per row)
    const int k = i & 31;
    const int chunk = k >> 4;    // 16 groups (64 dims) per chunk
    const int sub   = k & 15;

    float4 src = reinterpret_cast<const float4*>(W)[i];
    ushort4 o;
    o.x = f2bf(src.x); o.y = f2bf(src.y); o.z = f2bf(src.z); o.w = f2bf(src.w);
    reinterpret_cast<ushort4*>(Wb)[(size_t)chunk * (VOCAB * 16) + (size_t)v * 16 + sub] = o;

    if (i < NCELLS) out[i] = 0.0f;
}

// Kernel 2: one wave per (cell, chunk); blockIdx%8 steers chunk to XCD halves
// so each XCD's L2 caches one 4.1 MB slice.
// lane = (half = lane>>5, j = lane&31): per iter the wave loads 2 rows
// (tokens 2i, 2i+half), 4 B/lane (one bf162 = dims 2j,2j+1).
__global__ __launch_bounds__(256) void gather_kernel(
    const int*    __restrict__ x,       // [NCELLS, T]
    const ushort* __restrict__ Wb,      // [NCHUNK][VOCAB][CDIM] bf16 bits
    const float*  __restrict__ w_pred,  // [1, D]
    const float*  __restrict__ b_pred,  // [1]
    float*        __restrict__ out)     // [NCELLS] (zeroed by convert kernel)
{
    const int wave = threadIdx.x >> 6;
    const int lane = threadIdx.x & 63;

    const int slot  = blockIdx.x & 7;
    const int chunk = slot >> 2;               // 4 XCDs per chunk
    const int sub   = slot & 3;
    const int g     = blockIdx.x >> 3;         // 0..3199
    const int cell  = ((g << 2) + sub) * 4 + wave;

    const int j    = lane & 31;   // dim-pair index: dims 2j, 2j+1 of chunk
    const int half = lane >> 5;

    // lane t (t = lane&31) holds token t's row offset (bf162 element units)
    int myidx  = __builtin_nontemporal_load(x + (size_t)cell * T + j);
    int rowoff = myidx << 5;      // token * 32 bf162 per row slice

    const __hip_bfloat162* __restrict__ tbl =
        reinterpret_cast<const __hip_bfloat162*>(Wb) + (size_t)chunk * CHUNK_ELEMS2;

    float ax = 0.0f, ay = 0.0f;
    #pragma unroll
    for (int i = 0; i < T / 2; ++i) {
        int e = __shfl(rowoff, 2 * i + half, 64);     // token 2i+half's row
        __hip_bfloat162 v = tbl[(uint32_t)(e + j)];   // saddr + 32b voffset
        float2 f = __bfloat1622float2(v);
        ax += f.x;
        ay += f.y;
    }
    // combine the two half-wave token subsets (even vs odd tokens)
    ax += __shfl_xor(ax, 32, 64);
    ay += __shfl_xor(ay, 32, 64);

    // lane owns chunk-dim d = 2j + half
    float p = (half ? ay : ax) * (1.0f / (float)T);
    float gl = gelu_fast(p);
    float wv = w_pred[chunk * CDIM + 2 * j + half];
    float s = gl * wv;

    #pragma unroll
    for (int off = 32; off >= 1; off >>= 1)
        s += __shfl_xor(s, off, 64);

    if (lane == 0) {
        if (chunk == 0) s += b_pred[0];
        atomicAdd(&out[cell], s);
    }
}

extern "C" void kernel_launch(void* const* d_in, const int* in_sizes, int n_in,
                              void* d_out, int out_size, void* d_ws, size_t ws_size,
                              hipStream_t stream) {
    const int*   x      = (const int*)  d_in[0];
    const float* W      = (const float*)d_in[1];
    const float* w_pred = (const float*)d_in[2];
    const float* b_pred = (const float*)d_in[3];
    float*       out    = (float*)d_out;
    ushort*      Wb     = (ushort*)d_ws;   // VOCAB*D*2 = 8.192 MB

    const int conv_groups = VOCAB * D / 4;                 // 1,024,000
    convert_W_kernel<<<conv_groups / 256, 256, 0, stream>>>(W, Wb, out);

    // 2 chunks x 12800 cell-blocks (4 cells per block) = 25600 blocks
    gather_kernel<<<NCHUNK * (NCELLS / 4), 256, 0, stream>>>(x, Wb, w_pred, b_pred, out);
}